// Round 10
// baseline (166.057 us; speedup 1.0000x reference)
//
#include <hip/hip_runtime.h>
#include <cstdint>
#include <math.h>

#define NB 4
#define NN 512
#define DH 128
#define NHEADS 8
#define NHID 16
#define ITILE 64
#define SENTINEL -1e30f

// ---- packed-f32 helpers (VOP3P, verified R9) ----
typedef __attribute__((ext_vector_type(2))) float f32x2;
__device__ __forceinline__ f32x2 pk_fma_blo(f32x2 a, f32x2 b, f32x2 c) {
    f32x2 d;
    asm("v_pk_fma_f32 %0, %1, %2, %3 op_sel_hi:[1,0,1]"
        : "=v"(d) : "v"(a), "v"(b), "v"(c));
    return d;
}
__device__ __forceinline__ f32x2 pk_fma_bhi(f32x2 a, f32x2 b, f32x2 c) {
    f32x2 d;
    asm("v_pk_fma_f32 %0, %1, %2, %3 op_sel:[0,1,0] op_sel_hi:[1,1,1]"
        : "=v"(d) : "v"(a), "v"(b), "v"(c));
    return d;
}
__device__ __forceinline__ f32x2 pk_add(f32x2 a, f32x2 b) {
    f32x2 d;
    asm("v_pk_add_f32 %0, %1, %2" : "=v"(d) : "v"(a), "v"(b));
    return d;
}

// ---- projection (R2-verified): 8 rows/block, head-major gl/gr [bh][512][16] ----
// proj-0 additionally packs the adjacency bitmask (fold: saves a dispatch).
__global__ __launch_bounds__(256) void proj_kernel(
    const float* __restrict__ h, const float* __restrict__ X,
    const float* __restrict__ Win,
    const float* __restrict__ Wl, const float* __restrict__ Wr,
    float* __restrict__ gl, float* __restrict__ gr,
    const int* __restrict__ adj, uint32_t* __restrict__ adjb)
{
    __shared__ __align__(16) float s_h[8][DH];
    const int bn0 = blockIdx.x * 8;
    const int b   = bn0 >> 9;
    const int n0  = bn0 & 511;
    const int t   = threadIdx.x;

    if (X) {
        if (t < DH) {
            const float w0 = Win[t], w1 = Win[DH + t];
#pragma unroll
            for (int r = 0; r < 8; ++r) {
                const float x0 = X[(bn0 + r) * 2 + 0];
                const float x1 = X[(bn0 + r) * 2 + 1];
                s_h[r][t] = x0 * w0 + x1 * w1;
            }
        }
        // fold: pack adj bitmask for this block's 8 rows (once, layer 0)
        if (t < 128) {
            const int rg = bn0 + (t >> 4);
            const int w  = t & 15;
            const int4* p = (const int4*)(adj + (size_t)rg * NN + w * 32);
            uint32_t m = 0;
#pragma unroll
            for (int c = 0; c < 8; ++c) {
                const int4 v = p[c];
                m |= (v.x != 0 ? 1u : 0u) << (c * 4 + 0);
                m |= (v.y != 0 ? 1u : 0u) << (c * 4 + 1);
                m |= (v.z != 0 ? 1u : 0u) << (c * 4 + 2);
                m |= (v.w != 0 ? 1u : 0u) << (c * 4 + 3);
            }
            adjb[(size_t)rg * 16 + w] = m;
        }
    } else {
        for (int idx = t; idx < 8 * DH; idx += 256)
            s_h[idx >> 7][idx & 127] = h[(size_t)bn0 * DH + idx];
    }
    __syncthreads();

    const float* W = (t < DH) ? Wl : Wr;   // wave-uniform split
    float*       g = (t < DH) ? gl : gr;
    const int f128 = t & 127;
    float acc[8] = {};
    for (int k = 0; k < DH; k += 4) {
        const float w0 = W[(k + 0) * DH + f128];
        const float w1 = W[(k + 1) * DH + f128];
        const float w2 = W[(k + 2) * DH + f128];
        const float w3 = W[(k + 3) * DH + f128];
#pragma unroll
        for (int r = 0; r < 8; ++r) {
            const float4 hv = *(const float4*)&s_h[r][k];
            acc[r] += hv.x * w0 + hv.y * w1 + hv.z * w2 + hv.w * w3;
        }
    }
    const int hh = f128 >> 4, f = f128 & 15;
    float* dst = g + ((size_t)(b * NHEADS + hh) * NN + n0) * NHID + f;
#pragma unroll
    for (int r = 0; r < 8; ++r)
        dst[r * NHID] = acc[r];
}

// ---- attention v6: 1024 threads/block, grid 256 -> 16 waves/CU (4/SIMD) ----
// Block (b, hh, it): ITILE=64 rows. il = t&31 -> rows (i0+il, i0+il+32);
// js = t>>5 in [0,32) -> 16-j slice. Factored-lrelu score, packed math,
// two-pass register softmax. 32-slice merge is hierarchical: slices 16-31
// park raw partials in LDS (aliasing dead planes), slices 0-15 fold them
// flash-style, then the R2-verified 16-slice merge runs. attn-0 zeroes out[].
__global__ __launch_bounds__(1024) void attn_kernel(
    const float* __restrict__ gl, const float* __restrict__ gr,
    const uint32_t* __restrict__ adjb, const float* __restrict__ a_vec,
    float* __restrict__ h_out,
    const float* __restrict__ Wout, float* __restrict__ out,
    const int zero_out)
{
    __shared__ __align__(16) float smem[21696];   // 86,784 B
    float* s_gl  = smem;                  // [512][16]
    float* s_gr  = smem + 8192;           // [512][16]
    float* scr   = smem;                  // alias: [16][64][16] (planes dead)
    float* s_dgl = smem + 16384;          // [512]
    float* s_dgr = smem + 16896;          // [512]
    float* s_m   = smem + 17408;          // [32][65]
    float* s_l   = smem + 19488;          // [32][65]
    float* s_M   = smem + 21568;          // [64]
    float* s_inv = smem + 21632;          // [64]

    const int blk = blockIdx.x;           // 256 = bh*8 + it
    const int it  = blk & 7;
    const int bh  = blk >> 3;
    const int b   = bh >> 3;
    const int hh  = bh & 7;
    const int i0  = it * ITILE;
    const int t   = threadIdx.x;
    const int il  = t & 31;
    const int js  = t >> 5;               // [0,32): 16-j slice
    const int r0  = i0 + il;
    const int r1  = r0 + 32;
    const int jbase = js * 16;

    // ---- stage planes (coalesced 64KB); keep regs for dgl/dgr dots ----
    const float4* pgl = (const float4*)(gl + (size_t)bh * NN * NHID);
    const float4* pgr = (const float4*)(gr + (size_t)bh * NN * NHID);
    float4 rl[2], rr[2];
#pragma unroll
    for (int k = 0; k < 2; ++k) { rl[k] = pgl[k * 1024 + t]; rr[k] = pgr[k * 1024 + t]; }

    // masks: 16 bits for this slice
    const uint32_t wrd0 = adjb[((size_t)(b * NN + r0)) * 16 + (js >> 1)];
    const uint32_t wrd1 = adjb[((size_t)(b * NN + r1)) * 16 + (js >> 1)];
    const uint32_t mask0 = (wrd0 >> ((js & 1) * 16)) & 0xFFFFu;
    const uint32_t mask1 = (wrd1 >> ((js & 1) * 16)) & 0xFFFFu;

    // gri for own 2 rows from global (L2-hot), as f32x2 pairs
    f32x2 gri0p[8], gri1p[8];
#pragma unroll
    for (int q = 0; q < 4; ++q) {
        const float4 v0 = pgr[r0 * 4 + q];
        const float4 v1 = pgr[r1 * 4 + q];
        gri0p[2*q+0] = (f32x2){v0.x, v0.y}; gri0p[2*q+1] = (f32x2){v0.z, v0.w};
        gri1p[2*q+0] = (f32x2){v1.x, v1.y}; gri1p[2*q+1] = (f32x2){v1.z, v1.w};
    }

    float a[16];   // uniform addr -> scalar regs
#pragma unroll
    for (int q = 0; q < 4; ++q) {
        const float4 v = ((const float4*)a_vec)[q];
        a[4*q+0] = v.x; a[4*q+1] = v.y; a[4*q+2] = v.z; a[4*q+3] = v.w;
    }

    {   // LDS stores of the staged planes
        float4* dl = (float4*)s_gl;
        float4* dr = (float4*)s_gr;
#pragma unroll
        for (int k = 0; k < 2; ++k) { dl[k * 1024 + t] = rl[k]; dr[k * 1024 + t] = rr[k]; }
    }
    {   // dgl[j]=a.gl[j], dgr[j]=a.gr[j] via quad shuffle on staging regs
        const float4 aq = ((const float4*)a_vec)[t & 3];
#pragma unroll
        for (int k = 0; k < 2; ++k) {
            float pl = rl[k].x * aq.x + rl[k].y * aq.y + rl[k].z * aq.z + rl[k].w * aq.w;
            float pr = rr[k].x * aq.x + rr[k].y * aq.y + rr[k].z * aq.z + rr[k].w * aq.w;
            pl += __shfl_xor(pl, 1); pl += __shfl_xor(pl, 2);
            pr += __shfl_xor(pr, 1); pr += __shfl_xor(pr, 2);
            if ((t & 3) == 0) {
                const int row = k * 256 + (t >> 2);
                s_dgl[row] = pl;
                s_dgr[row] = pr;
            }
        }
    }
    __syncthreads();

    // ---- pass 1: scores for 2 rows x 16 j (packed adds, abs-modifier fma) ----
    const float c0 = 0.6f * s_dgr[r0];
    const float c1 = 0.6f * s_dgr[r1];
    float sc0[16], sc1[16];
#pragma unroll
    for (int jj = 0; jj < 16; ++jj) {
        const int j = jbase + jj;
        const float4* pg = (const float4*)(s_gl + j * NHID);
        const float dj = s_dgl[j];
        float s0 = 0.f, s1 = 0.f;
#pragma unroll
        for (int q = 0; q < 4; ++q) {
            const float4 g = pg[q];       // 2 addrs/wave -> broadcast
            const f32x2 Ga = {g.x, g.y}, Gb = {g.z, g.w};
            const f32x2 v0a = pk_add(Ga, gri0p[2*q+0]);
            const f32x2 v0b = pk_add(Gb, gri0p[2*q+1]);
            const f32x2 v1a = pk_add(Ga, gri1p[2*q+0]);
            const f32x2 v1b = pk_add(Gb, gri1p[2*q+1]);
            s0 = fmaf(a[4*q+0], fabsf(v0a.x), s0);
            s0 = fmaf(a[4*q+1], fabsf(v0a.y), s0);
            s0 = fmaf(a[4*q+2], fabsf(v0b.x), s0);
            s0 = fmaf(a[4*q+3], fabsf(v0b.y), s0);
            s1 = fmaf(a[4*q+0], fabsf(v1a.x), s1);
            s1 = fmaf(a[4*q+1], fabsf(v1a.y), s1);
            s1 = fmaf(a[4*q+2], fabsf(v1b.x), s1);
            s1 = fmaf(a[4*q+3], fabsf(v1b.y), s1);
        }
        const float b0 = fmaf(0.6f, dj, c0);
        const float b1 = fmaf(0.6f, dj, c1);
        sc0[jj] = ((mask0 >> jj) & 1u) ? fmaf(0.4f, s0, b0) : SENTINEL;
        sc1[jj] = ((mask1 >> jj) & 1u) ? fmaf(0.4f, s1, b1) : SENTINEL;
    }

    // ---- in-register softmax (two-pass over 16) ----
    float m0 = sc0[0], m1 = sc1[0];
#pragma unroll
    for (int jj = 1; jj < 16; ++jj) { m0 = fmaxf(m0, sc0[jj]); m1 = fmaxf(m1, sc1[jj]); }
    float l0 = 0.f, l1 = 0.f;
#pragma unroll
    for (int jj = 0; jj < 16; ++jj) {
        sc0[jj] = __expf(sc0[jj] - m0); l0 += sc0[jj];
        sc1[jj] = __expf(sc1[jj] - m1); l1 += sc1[jj];
    }
    s_m[js * 65 + il]      = m0;
    s_m[js * 65 + il + 32] = m1;
    s_l[js * 65 + il]      = l0;
    s_l[js * 65 + il + 32] = l1;

    // ---- pass 2: PV aggregation (packed, {p0,p1} broadcast) ----
    f32x2 acc0p[8], acc1p[8];
#pragma unroll
    for (int f = 0; f < 8; ++f) { acc0p[f] = (f32x2){0.f, 0.f}; acc1p[f] = (f32x2){0.f, 0.f}; }
#pragma unroll
    for (int jj = 0; jj < 16; ++jj) {
        const int j = jbase + jj;
        const float4* pg = (const float4*)(s_gr + j * NHID);
        const f32x2 pp = {sc0[jj], sc1[jj]};
#pragma unroll
        for (int q = 0; q < 4; ++q) {
            const float4 g = pg[q];       // broadcast
            const f32x2 Ga = {g.x, g.y}, Gb = {g.z, g.w};
            acc0p[2*q+0] = pk_fma_blo(Ga, pp, acc0p[2*q+0]);
            acc0p[2*q+1] = pk_fma_blo(Gb, pp, acc0p[2*q+1]);
            acc1p[2*q+0] = pk_fma_bhi(Ga, pp, acc1p[2*q+0]);
            acc1p[2*q+1] = pk_fma_bhi(Gb, pp, acc1p[2*q+1]);
        }
    }
    __syncthreads();                      // retires plane reads; scratch alias safe

    // ---- merge round A: slices 16-31 park raw partials in scratch ----
    const int swz = il & 3;
    if (js >= 16) {
        float* basep = scr + (js - 16) * 1024;
#pragma unroll
        for (int q = 0; q < 4; ++q) {
            float4 v0, v1;
            v0.x = acc0p[2*q+0].x; v0.y = acc0p[2*q+0].y;
            v0.z = acc0p[2*q+1].x; v0.w = acc0p[2*q+1].y;
            v1.x = acc1p[2*q+0].x; v1.y = acc1p[2*q+0].y;
            v1.z = acc1p[2*q+1].x; v1.w = acc1p[2*q+1].y;
            *(float4*)(basep + il * 16        + 4 * (q ^ swz)) = v0;
            *(float4*)(basep + (il + 32) * 16 + 4 * (q ^ swz)) = v1;
        }
    }
    __syncthreads();

    // ---- merge round A fold: slices 0-15 absorb partner (js+16) ----
    if (js < 16) {
        const float pm0 = s_m[(js + 16) * 65 + il];
        const float pm1 = s_m[(js + 16) * 65 + il + 32];
        const float pl0 = s_l[(js + 16) * 65 + il];
        const float pl1 = s_l[(js + 16) * 65 + il + 32];
        const float nm0 = fmaxf(m0, pm0), nm1 = fmaxf(m1, pm1);
        const float wa0 = __expf(m0 - nm0), wb0 = __expf(pm0 - nm0);
        const float wa1 = __expf(m1 - nm1), wb1 = __expf(pm1 - nm1);
        l0 = l0 * wa0 + pl0 * wb0;
        l1 = l1 * wa1 + pl1 * wb1;
        float* basep = scr + js * 1024;
#pragma unroll
        for (int q = 0; q < 4; ++q) {
            const float4 o0 = *(const float4*)(basep + il * 16        + 4 * (q ^ swz));
            const float4 o1 = *(const float4*)(basep + (il + 32) * 16 + 4 * (q ^ swz));
            acc0p[2*q+0].x = acc0p[2*q+0].x * wa0 + o0.x * wb0;
            acc0p[2*q+0].y = acc0p[2*q+0].y * wa0 + o0.y * wb0;
            acc0p[2*q+1].x = acc0p[2*q+1].x * wa0 + o0.z * wb0;
            acc0p[2*q+1].y = acc0p[2*q+1].y * wa0 + o0.w * wb0;
            acc1p[2*q+0].x = acc1p[2*q+0].x * wa1 + o1.x * wb1;
            acc1p[2*q+0].y = acc1p[2*q+0].y * wa1 + o1.y * wb1;
            acc1p[2*q+1].x = acc1p[2*q+1].x * wa1 + o1.z * wb1;
            acc1p[2*q+1].y = acc1p[2*q+1].y * wa1 + o1.w * wb1;
        }
        m0 = nm0; m1 = nm1;
        s_m[js * 65 + il]      = m0;
        s_m[js * 65 + il + 32] = m1;
        s_l[js * 65 + il]      = l0;
        s_l[js * 65 + il + 32] = l1;
    }
    __syncthreads();

    if (t < 64) {                         // per-row global max + denom over 16 slices
        float M = SENTINEL;
#pragma unroll
        for (int k = 0; k < 16; ++k) M = fmaxf(M, s_m[k * 65 + t]);
        float L = 0.f;
#pragma unroll
        for (int k = 0; k < 16; ++k) L += s_l[k * 65 + t] * __expf(s_m[k * 65 + t] - M);
        s_M[t]   = M;
        s_inv[t] = 1.f / L;
    }
    __syncthreads();

    if (js < 16) {                        // scaled partials into scratch
        const float k0 = __expf(m0 - s_M[il])      * s_inv[il];
        const float k1 = __expf(m1 - s_M[il + 32]) * s_inv[il + 32];
        float* basep = scr + js * 1024;
#pragma unroll
        for (int q = 0; q < 4; ++q) {
            float4 v0, v1;
            v0.x = acc0p[2*q+0].x * k0; v0.y = acc0p[2*q+0].y * k0;
            v0.z = acc0p[2*q+1].x * k0; v0.w = acc0p[2*q+1].y * k0;
            v1.x = acc1p[2*q+0].x * k1; v1.y = acc1p[2*q+0].y * k1;
            v1.z = acc1p[2*q+1].x * k1; v1.w = acc1p[2*q+1].y * k1;
            *(float4*)(basep + il * 16        + 4 * (q ^ swz)) = v0;
            *(float4*)(basep + (il + 32) * 16 + 4 * (q ^ swz)) = v1;
        }
    }
    __syncthreads();

    {   // final reduce: thread (i = t>>4 in [0,64), f = t&15) -> one row each
        const int i  = t >> 4;
        const int f  = t & 15;
        const int e  = f & 3, qf = f >> 2;
        const int w  = i * 16 + 4 * (qf ^ (i & 3)) + e;
        float o = 0.f;
#pragma unroll
        for (int k = 0; k < 16; ++k) o += scr[k * 1024 + w];
        const int grow = i0 + i;
        if (Wout) {                       // fused h @ W_out partial per head
            float v = o * Wout[hh * NHID + f];
#pragma unroll
            for (int off = 8; off; off >>= 1) v += __shfl_xor(v, off);
            if (f == 0) atomicAdd(out + b * NN + grow, v);
        } else {
            h_out[((size_t)(b * NN + grow)) * DH + hh * NHID + f] = o;
        }
    }

    // attn-0 zeroes the atomic target for attn-2 (stream-ordered)
    if (zero_out && blk < 2) out[blk * 1024 + t] = 0.f;
}

extern "C" void kernel_launch(void* const* d_in, const int* in_sizes, int n_in,
                              void* d_out, int out_size, void* d_ws, size_t ws_size,
                              hipStream_t stream) {
    const float* X    = (const float*)d_in[0];   // [4,512,2]
    const int*   adj  = (const int*)  d_in[1];   // [4,512,512]
    const float* Win  = (const float*)d_in[2];   // [2,128]
    const float* Wl   = (const float*)d_in[3];   // [3,128,128]
    const float* Wr   = (const float*)d_in[4];   // [3,128,128]
    const float* Aa   = (const float*)d_in[5];   // [3,16]
    const float* Wout = (const float*)d_in[6];   // [128,1]
    float* out = (float*)d_out;                  // [4,512] fp32

    float*    ws   = (float*)d_ws;
    float*    h_a  = ws;                         // 1 MB
    float*    h_b  = ws + 262144;                // 1 MB
    float*    gl   = ws + 524288;                // 1 MB (head-major)
    float*    gr   = ws + 786432;                // 1 MB
    uint32_t* adjb = (uint32_t*)(ws + 1048576);  // 128 KB

    proj_kernel<<<NB * NN / 8, 256, 0, stream>>>(
        nullptr, X, Win, Wl, Wr, gl, gr, adj, adjb);
    attn_kernel<<<NB * NHEADS * (NN / ITILE), 1024, 0, stream>>>(
        gl, gr, adjb, Aa, h_a, nullptr, out, 1);

    proj_kernel<<<NB * NN / 8, 256, 0, stream>>>(
        h_a, nullptr, Win, Wl + DH * DH, Wr + DH * DH, gl, gr, adj, adjb);
    attn_kernel<<<NB * NHEADS * (NN / ITILE), 1024, 0, stream>>>(
        gl, gr, adjb, Aa + NHID, h_b, nullptr, out, 0);

    proj_kernel<<<NB * NN / 8, 256, 0, stream>>>(
        h_b, nullptr, Win, Wl + 2 * DH * DH, Wr + 2 * DH * DH, gl, gr, adj, adjb);
    attn_kernel<<<NB * NHEADS * (NN / ITILE), 1024, 0, stream>>>(
        gl, gr, adjb, Aa + 2 * NHID, nullptr, Wout, out, 0);
}

// Round 11
// 157.894 us; speedup vs baseline: 1.0517x; 1.0517x over previous
//
#include <hip/hip_runtime.h>
#include <cstdint>
#include <math.h>

#define NB 4
#define NN 512
#define DH 128
#define NHEADS 8
#define NHID 16
#define ITILE 64
#define SENTINEL -1e30f

// ---- packed-f32 helpers (VOP3P, verified R9) ----
typedef __attribute__((ext_vector_type(2))) float f32x2;
__device__ __forceinline__ f32x2 pk_fma_blo(f32x2 a, f32x2 b, f32x2 c) {
    f32x2 d;
    asm("v_pk_fma_f32 %0, %1, %2, %3 op_sel_hi:[1,0,1]"
        : "=v"(d) : "v"(a), "v"(b), "v"(c));
    return d;
}
__device__ __forceinline__ f32x2 pk_fma_bhi(f32x2 a, f32x2 b, f32x2 c) {
    f32x2 d;
    asm("v_pk_fma_f32 %0, %1, %2, %3 op_sel:[0,1,0] op_sel_hi:[1,1,1]"
        : "=v"(d) : "v"(a), "v"(b), "v"(c));
    return d;
}
__device__ __forceinline__ f32x2 pk_add(f32x2 a, f32x2 b) {
    f32x2 d;
    asm("v_pk_add_f32 %0, %1, %2" : "=v"(d) : "v"(a), "v"(b));
    return d;
}

// ---- fully-fused GAT layer v6: R9 (155us best) + pipelined proj loads ----
// 3 dispatches total (R10 proved split structures lose ~4us per extra
// dispatch boundary). Only change vs R9: the proj hT loads are software-
// pipelined 2x8-deep (load B while consuming A) and the first octet is
// issued at kernel entry so its L2 latency hides under W staging + mask
// handling + the barrier. R9 drained vmcnt at every 16-batch boundary
// (~8 x ~400cy exposed with only 2 waves/SIMD). Math order unchanged ->
// bit-identical (absmax 0.0).
__global__ __launch_bounds__(512, 1) void gat_layer(
    const int lay,
    const float* __restrict__ X,
    const float* __restrict__ hTin, float* __restrict__ hTout,
    const float* __restrict__ Win,
    const float* __restrict__ WlL, const float* __restrict__ WrL,
    const float* __restrict__ a_vec, const float* __restrict__ Wout,
    float* __restrict__ out, uint32_t* __restrict__ adjb,
    const int* __restrict__ adj)
{
    __shared__ __align__(16) float smem[23968];   // 95,872 B -> 1 block/CU
    float* s_W   = smem;                  // [128][32] cols 0-15 Wl, 16-31 Wr
    float* s_Win = smem + 4096;           // [2][128] (layer 0 only)
    float4* Sgl  = (float4*)(smem + 4352);   // [4][512] f-major gl chunks
    float4* Sgr  = (float4*)(smem + 12544);  // [4][512] f-major gr chunks
    float* s_dgl = smem + 20736;          // [512]
    float* s_dgr = smem + 21248;          // [512]
    float* s_m   = smem + 21760;          // [16][65]
    float* s_l   = smem + 22800;          // [16][65]
    float* s_M   = smem + 23840;          // [64]
    float* s_inv = smem + 23904;          // [64]
    float* s_acc = smem;                  // alias [16][64][16], dead post-PV

    const int blk = blockIdx.x;           // 256 = ((b*8+hh)*8) + it
    const int it  = blk & 7;
    const int bh  = blk >> 3;
    const int b   = bh >> 3;
    const int hh  = bh & 7;
    const int i0  = it * ITILE;
    const int t   = threadIdx.x;
    const int il  = t & 31;
    const int js  = t >> 5;               // [0,16)
    const int r0  = i0 + il;
    const int r1  = r0 + 32;

    // ---- proj indices + EARLY issue of first load octet (L2 latency hides
    //      under W staging + mask handling + barrier) ----
    const int c4 = t >> 7;                // wave-uniform (2 waves per c4)
    const int rq = t & 127;
    const float* hT = nullptr;
    float4 hbA[8], hbB[8];
    if (lay > 0) {
        hT = hTin + (size_t)b * DH * NN + 4 * rq;
#pragma unroll
        for (int u = 0; u < 8; ++u)
            hbA[u] = *(const float4*)&hT[(size_t)u * NN];
    }

    // ---- stage W head-slices -> s_W[k][32]; Win (layer 0) ----
    for (int c = t; c < 1024; c += 512) {
        const int k = c >> 3, j = c & 7;
        if (j < 4)
            *(float4*)&s_W[k * 32 + j * 4] =
                *(const float4*)&WlL[k * DH + hh * NHID + j * 4];
        else
            *(float4*)&s_W[k * 32 + 16 + (j - 4) * 4] =
                *(const float4*)&WrL[k * DH + hh * NHID + (j - 4) * 4];
    }
    if (lay == 0 && t < 64) ((float4*)s_Win)[t] = ((const float4*)Win)[t];

    float a[16];
#pragma unroll
    for (int q = 0; q < 4; ++q) {
        const float4 v = ((const float4*)a_vec)[q];
        a[4*q+0] = v.x; a[4*q+1] = v.y; a[4*q+2] = v.z; a[4*q+3] = v.w;
    }

    // ---- masks: layer 0 packs from adj (and stores for reuse); else load ----
    uint32_t mask0, mask1;
    if (lay == 0) {
        const int4* p0 = (const int4*)(adj + ((size_t)(b * NN + r0)) * NN + js * 32);
        const int4* p1 = (const int4*)(adj + ((size_t)(b * NN + r1)) * NN + js * 32);
        uint32_t m0 = 0, m1 = 0;
#pragma unroll
        for (int c = 0; c < 8; ++c) {
            const int4 v0 = p0[c], v1 = p1[c];
            m0 |= (v0.x != 0 ? 1u : 0u) << (c * 4 + 0);
            m0 |= (v0.y != 0 ? 1u : 0u) << (c * 4 + 1);
            m0 |= (v0.z != 0 ? 1u : 0u) << (c * 4 + 2);
            m0 |= (v0.w != 0 ? 1u : 0u) << (c * 4 + 3);
            m1 |= (v1.x != 0 ? 1u : 0u) << (c * 4 + 0);
            m1 |= (v1.y != 0 ? 1u : 0u) << (c * 4 + 1);
            m1 |= (v1.z != 0 ? 1u : 0u) << (c * 4 + 2);
            m1 |= (v1.w != 0 ? 1u : 0u) << (c * 4 + 3);
        }
        mask0 = m0; mask1 = m1;
        adjb[((size_t)(b * NN + r0)) * 16 + js] = m0;  // 8 hh-blocks same value: benign
        adjb[((size_t)(b * NN + r1)) * 16 + js] = m1;
    } else {
        mask0 = adjb[((size_t)(b * NN + r0)) * 16 + js];
        mask1 = adjb[((size_t)(b * NN + r1)) * 16 + js];
    }
    __syncthreads();                      // s_W/s_Win staged

    // ---- proj: thread (c4, rq) -> rows 4rq..4rq+3, cols c4*8..+7 ----
    {
        const float* wcol = s_W + ((c4 >> 1) * 16 + (c4 & 1) * 8);
        f32x2 acc2[4][4];                 // [row][colpair]
#pragma unroll
        for (int m = 0; m < 4; ++m)
#pragma unroll
            for (int c = 0; c < 4; ++c) acc2[m][c] = (f32x2){0.f, 0.f};

        if (lay == 0) {
            const float4 xa = *(const float4*)&X[(size_t)(b * NN + 4 * rq) * 2];
            const float4 xb = *(const float4*)&X[(size_t)(b * NN + 4 * rq) * 2 + 4];
            const float x0[4] = {xa.x, xa.z, xb.x, xb.z};
            const float x1[4] = {xa.y, xa.w, xb.y, xb.w};
#pragma unroll 2
            for (int kq = 0; kq < 32; ++kq) {
                const float4 w0 = *(const float4*)&s_Win[kq * 4];
                const float4 w1 = *(const float4*)&s_Win[128 + kq * 4];
                const float w0a[4] = {w0.x, w0.y, w0.z, w0.w};
                const float w1a[4] = {w1.x, w1.y, w1.z, w1.w};
#pragma unroll
                for (int kk = 0; kk < 4; ++kk) {
                    const int k = kq * 4 + kk;
                    const float4 wa = *(const float4*)&wcol[k * 32];
                    const float4 wb = *(const float4*)&wcol[k * 32 + 4];
                    const f32x2 W0 = {wa.x, wa.y}, W1 = {wa.z, wa.w};
                    const f32x2 W2 = {wb.x, wb.y}, W3 = {wb.z, wb.w};
                    const float hm0 = x0[0] * w0a[kk] + x1[0] * w1a[kk];
                    const float hm1 = x0[1] * w0a[kk] + x1[1] * w1a[kk];
                    const float hm2 = x0[2] * w0a[kk] + x1[2] * w1a[kk];
                    const float hm3 = x0[3] * w0a[kk] + x1[3] * w1a[kk];
                    const f32x2 H0 = {hm0, hm1}, H1 = {hm2, hm3};
                    acc2[0][0] = pk_fma_blo(W0, H0, acc2[0][0]);
                    acc2[0][1] = pk_fma_blo(W1, H0, acc2[0][1]);
                    acc2[0][2] = pk_fma_blo(W2, H0, acc2[0][2]);
                    acc2[0][3] = pk_fma_blo(W3, H0, acc2[0][3]);
                    acc2[1][0] = pk_fma_bhi(W0, H0, acc2[1][0]);
                    acc2[1][1] = pk_fma_bhi(W1, H0, acc2[1][1]);
                    acc2[1][2] = pk_fma_bhi(W2, H0, acc2[1][2]);
                    acc2[1][3] = pk_fma_bhi(W3, H0, acc2[1][3]);
                    acc2[2][0] = pk_fma_blo(W0, H1, acc2[2][0]);
                    acc2[2][1] = pk_fma_blo(W1, H1, acc2[2][1]);
                    acc2[2][2] = pk_fma_blo(W2, H1, acc2[2][2]);
                    acc2[2][3] = pk_fma_blo(W3, H1, acc2[2][3]);
                    acc2[3][0] = pk_fma_bhi(W0, H1, acc2[3][0]);
                    acc2[3][1] = pk_fma_bhi(W1, H1, acc2[3][1]);
                    acc2[3][2] = pk_fma_bhi(W2, H1, acc2[3][2]);
                    acc2[3][3] = pk_fma_bhi(W3, H1, acc2[3][3]);
                }
            }
        } else {
            // 2x8-deep software pipeline: 8 loads always in flight while the
            // other 8 are consumed (R9 drained at every 16-batch boundary).
#pragma unroll 1
            for (int kb = 0; kb < DH; kb += 16) {
#pragma unroll
                for (int u = 0; u < 8; ++u)
                    hbB[u] = *(const float4*)&hT[(size_t)(kb + 8 + u) * NN];
#pragma unroll
                for (int u = 0; u < 8; ++u) {
                    const int k = kb + u;
                    const float4 wa = *(const float4*)&wcol[k * 32];  // broadcast
                    const float4 wb = *(const float4*)&wcol[k * 32 + 4];
                    const f32x2 W0 = {wa.x, wa.y}, W1 = {wa.z, wa.w};
                    const f32x2 W2 = {wb.x, wb.y}, W3 = {wb.z, wb.w};
                    const f32x2 H0 = {hbA[u].x, hbA[u].y}, H1 = {hbA[u].z, hbA[u].w};
                    acc2[0][0] = pk_fma_blo(W0, H0, acc2[0][0]);
                    acc2[0][1] = pk_fma_blo(W1, H0, acc2[0][1]);
                    acc2[0][2] = pk_fma_blo(W2, H0, acc2[0][2]);
                    acc2[0][3] = pk_fma_blo(W3, H0, acc2[0][3]);
                    acc2[1][0] = pk_fma_bhi(W0, H0, acc2[1][0]);
                    acc2[1][1] = pk_fma_bhi(W1, H0, acc2[1][1]);
                    acc2[1][2] = pk_fma_bhi(W2, H0, acc2[1][2]);
                    acc2[1][3] = pk_fma_bhi(W3, H0, acc2[1][3]);
                    acc2[2][0] = pk_fma_blo(W0, H1, acc2[2][0]);
                    acc2[2][1] = pk_fma_blo(W1, H1, acc2[2][1]);
                    acc2[2][2] = pk_fma_blo(W2, H1, acc2[2][2]);
                    acc2[2][3] = pk_fma_blo(W3, H1, acc2[2][3]);
                    acc2[3][0] = pk_fma_bhi(W0, H1, acc2[3][0]);
                    acc2[3][1] = pk_fma_bhi(W1, H1, acc2[3][1]);
                    acc2[3][2] = pk_fma_bhi(W2, H1, acc2[3][2]);
                    acc2[3][3] = pk_fma_bhi(W3, H1, acc2[3][3]);
                }
                if (kb + 16 < DH) {
#pragma unroll
                    for (int u = 0; u < 8; ++u)
                        hbA[u] = *(const float4*)&hT[(size_t)(kb + 16 + u) * NN];
                }
#pragma unroll
                for (int u = 0; u < 8; ++u) {
                    const int k = kb + 8 + u;
                    const float4 wa = *(const float4*)&wcol[k * 32];
                    const float4 wb = *(const float4*)&wcol[k * 32 + 4];
                    const f32x2 W0 = {wa.x, wa.y}, W1 = {wa.z, wa.w};
                    const f32x2 W2 = {wb.x, wb.y}, W3 = {wb.z, wb.w};
                    const f32x2 H0 = {hbB[u].x, hbB[u].y}, H1 = {hbB[u].z, hbB[u].w};
                    acc2[0][0] = pk_fma_blo(W0, H0, acc2[0][0]);
                    acc2[0][1] = pk_fma_blo(W1, H0, acc2[0][1]);
                    acc2[0][2] = pk_fma_blo(W2, H0, acc2[0][2]);
                    acc2[0][3] = pk_fma_blo(W3, H0, acc2[0][3]);
                    acc2[1][0] = pk_fma_bhi(W0, H0, acc2[1][0]);
                    acc2[1][1] = pk_fma_bhi(W1, H0, acc2[1][1]);
                    acc2[1][2] = pk_fma_bhi(W2, H0, acc2[1][2]);
                    acc2[1][3] = pk_fma_bhi(W3, H0, acc2[1][3]);
                    acc2[2][0] = pk_fma_blo(W0, H1, acc2[2][0]);
                    acc2[2][1] = pk_fma_blo(W1, H1, acc2[2][1]);
                    acc2[2][2] = pk_fma_blo(W2, H1, acc2[2][2]);
                    acc2[2][3] = pk_fma_blo(W3, H1, acc2[2][3]);
                    acc2[3][0] = pk_fma_bhi(W0, H1, acc2[3][0]);
                    acc2[3][1] = pk_fma_bhi(W1, H1, acc2[3][1]);
                    acc2[3][2] = pk_fma_bhi(W2, H1, acc2[3][2]);
                    acc2[3][3] = pk_fma_bhi(W3, H1, acc2[3][3]);
                }
            }
        }
        // write f-major plane slices
        float4* Sg = (c4 < 2) ? Sgl : Sgr;
        const int q0 = (c4 & 1) * 2;
#pragma unroll
        for (int m = 0; m < 4; ++m) {
            float4 v0, v1;
            v0.x = acc2[m][0].x; v0.y = acc2[m][0].y;
            v0.z = acc2[m][1].x; v0.w = acc2[m][1].y;
            v1.x = acc2[m][2].x; v1.y = acc2[m][2].y;
            v1.z = acc2[m][3].x; v1.w = acc2[m][3].y;
            Sg[q0 * 512       + 4 * rq + m] = v0;
            Sg[(q0 + 1) * 512 + 4 * rq + m] = v1;
        }
    }
    __syncthreads();                      // planes complete

    {   // dgl[t] = a . gl[t], dgr[t] = a . gr[t] (lane-consecutive reads)
        float dl = 0.f, dr = 0.f;
#pragma unroll
        for (int q = 0; q < 4; ++q) {
            const float4 vl = Sgl[q * 512 + t];
            const float4 vr = Sgr[q * 512 + t];
            dl = fmaf(a[4*q+0], vl.x, dl); dl = fmaf(a[4*q+1], vl.y, dl);
            dl = fmaf(a[4*q+2], vl.z, dl); dl = fmaf(a[4*q+3], vl.w, dl);
            dr = fmaf(a[4*q+0], vr.x, dr); dr = fmaf(a[4*q+1], vr.y, dr);
            dr = fmaf(a[4*q+2], vr.z, dr); dr = fmaf(a[4*q+3], vr.w, dr);
        }
        s_dgl[t] = dl;
        s_dgr[t] = dr;
    }
    __syncthreads();                      // dgl/dgr ready

    // ---- gri for own 2 rows (as f32x2 pairs) ----
    f32x2 gri0p[8], gri1p[8];
#pragma unroll
    for (int q = 0; q < 4; ++q) {
        const float4 v0 = Sgr[q * 512 + r0];
        const float4 v1 = Sgr[q * 512 + r1];
        gri0p[2*q+0] = (f32x2){v0.x, v0.y}; gri0p[2*q+1] = (f32x2){v0.z, v0.w};
        gri1p[2*q+0] = (f32x2){v1.x, v1.y}; gri1p[2*q+1] = (f32x2){v1.z, v1.w};
    }

    // ---- pass 1: scores for 2 rows x 32 j (pk_add + scalar |.| fma) ----
    const float c0 = 0.6f * s_dgr[r0];
    const float c1 = 0.6f * s_dgr[r1];
    const int jbase = js * 32;
    float sc0[32], sc1[32];
#pragma unroll
    for (int jj = 0; jj < 32; ++jj) {
        const int j = jbase + jj;
        const float dj = s_dgl[j];
        float s0 = 0.f, s1 = 0.f;
#pragma unroll
        for (int q = 0; q < 4; ++q) {
            const float4 g = Sgl[q * 512 + j];   // uniform j -> broadcast
            const f32x2 Ga = {g.x, g.y}, Gb = {g.z, g.w};
            const f32x2 v0a = pk_add(Ga, gri0p[2*q+0]);
            const f32x2 v0b = pk_add(Gb, gri0p[2*q+1]);
            const f32x2 v1a = pk_add(Ga, gri1p[2*q+0]);
            const f32x2 v1b = pk_add(Gb, gri1p[2*q+1]);
            s0 = fmaf(a[4*q+0], fabsf(v0a.x), s0);
            s0 = fmaf(a[4*q+1], fabsf(v0a.y), s0);
            s0 = fmaf(a[4*q+2], fabsf(v0b.x), s0);
            s0 = fmaf(a[4*q+3], fabsf(v0b.y), s0);
            s1 = fmaf(a[4*q+0], fabsf(v1a.x), s1);
            s1 = fmaf(a[4*q+1], fabsf(v1a.y), s1);
            s1 = fmaf(a[4*q+2], fabsf(v1b.x), s1);
            s1 = fmaf(a[4*q+3], fabsf(v1b.y), s1);
        }
        const float b0 = fmaf(0.6f, dj, c0);
        const float b1 = fmaf(0.6f, dj, c1);
        sc0[jj] = ((mask0 >> jj) & 1u) ? fmaf(0.4f, s0, b0) : SENTINEL;
        sc1[jj] = ((mask1 >> jj) & 1u) ? fmaf(0.4f, s1, b1) : SENTINEL;
    }

    // ---- in-register softmax (two-pass) ----
    float m0 = sc0[0], m1 = sc1[0];
#pragma unroll
    for (int jj = 1; jj < 32; ++jj) { m0 = fmaxf(m0, sc0[jj]); m1 = fmaxf(m1, sc1[jj]); }
    float l0 = 0.f, l1 = 0.f;
#pragma unroll
    for (int jj = 0; jj < 32; ++jj) {
        sc0[jj] = __expf(sc0[jj] - m0); l0 += sc0[jj];
        sc1[jj] = __expf(sc1[jj] - m1); l1 += sc1[jj];
    }
    s_m[js * 65 + il]      = m0;
    s_m[js * 65 + il + 32] = m1;
    s_l[js * 65 + il]      = l0;
    s_l[js * 65 + il + 32] = l1;

    // ---- pass 2: PV aggregation (packed, {p0,p1} op_sel broadcast) ----
    f32x2 acc0p[8], acc1p[8];
#pragma unroll
    for (int f = 0; f < 8; ++f) { acc0p[f] = (f32x2){0.f, 0.f}; acc1p[f] = (f32x2){0.f, 0.f}; }
#pragma unroll
    for (int jj = 0; jj < 32; ++jj) {
        const int j = jbase + jj;
        const f32x2 pp = {sc0[jj], sc1[jj]};
#pragma unroll
        for (int q = 0; q < 4; ++q) {
            const float4 g = Sgr[q * 512 + j];   // broadcast
            const f32x2 Ga = {g.x, g.y}, Gb = {g.z, g.w};
            acc0p[2*q+0] = pk_fma_blo(Ga, pp, acc0p[2*q+0]);
            acc0p[2*q+1] = pk_fma_blo(Gb, pp, acc0p[2*q+1]);
            acc1p[2*q+0] = pk_fma_bhi(Ga, pp, acc1p[2*q+0]);
            acc1p[2*q+1] = pk_fma_bhi(Gb, pp, acc1p[2*q+1]);
        }
    }
    __syncthreads();                      // retires plane reads + s_m/s_l writes

    if (t < 64) {                         // per-row global max + denom over 16 slices
        float M = SENTINEL;
#pragma unroll
        for (int k = 0; k < 16; ++k) M = fmaxf(M, s_m[k * 65 + t]);
        float L = 0.f;
#pragma unroll
        for (int k = 0; k < 16; ++k) L += s_l[k * 65 + t] * __expf(s_m[k * 65 + t] - M);
        s_M[t]   = M;
        s_inv[t] = 1.f / L;
    }
    __syncthreads();

    {   // scaled partials into aliased scratch; chunk-XOR swizzle
        const float k0 = __expf(m0 - s_M[il])      * s_inv[il];
        const float k1 = __expf(m1 - s_M[il + 32]) * s_inv[il + 32];
        const int swz = il & 3;
        float* base_a = s_acc + js * 1024;
#pragma unroll
        for (int q = 0; q < 4; ++q) {
            float4 v0, v1;
            v0.x = acc0p[2*q+0].x * k0; v0.y = acc0p[2*q+0].y * k0;
            v0.z = acc0p[2*q+1].x * k0; v0.w = acc0p[2*q+1].y * k0;
            v1.x = acc1p[2*q+0].x * k1; v1.y = acc1p[2*q+0].y * k1;
            v1.z = acc1p[2*q+1].x * k1; v1.w = acc1p[2*q+1].y * k1;
            *(float4*)(base_a + il * 16        + 4 * (q ^ swz)) = v0;
            *(float4*)(base_a + (il + 32) * 16 + 4 * (q ^ swz)) = v1;
        }
    }
    __syncthreads();

    {   // final reduce over 16 slices: thread (i = t>>4, f = t&15), 2 rows each
        const int i  = t >> 4;
        const int f  = t & 15;
        const int e  = f & 3, qf = f >> 2;
#pragma unroll
        for (int r = 0; r < 2; ++r) {
            const int lr = i + r * 32;
            const int w  = lr * 16 + 4 * (qf ^ (lr & 3)) + e;
            float o = 0.f;
#pragma unroll
            for (int k = 0; k < 16; ++k) o += s_acc[k * 1024 + w];
            const int grow = i0 + lr;
            if (Wout) {                   // fused h @ W_out partial per head
                float v = o * Wout[hh * NHID + f];
#pragma unroll
                for (int off = 8; off; off >>= 1) v += __shfl_xor(v, off);
                if (f == 0) atomicAdd(out + b * NN + grow, v);
            } else {                      // transposed activation for next layer
                hTout[((size_t)b * DH + hh * NHID + f) * NN + grow] = o;
            }
        }
    }

    // layer 1 zeroes the atomic target for layer 2 (stream-ordered)
    if (lay == 1 && blk < 4) out[blk * 512 + t] = 0.f;
}

extern "C" void kernel_launch(void* const* d_in, const int* in_sizes, int n_in,
                              void* d_out, int out_size, void* d_ws, size_t ws_size,
                              hipStream_t stream) {
    const float* X    = (const float*)d_in[0];   // [4,512,2]
    const int*   adj  = (const int*)  d_in[1];   // [4,512,512]
    const float* Win  = (const float*)d_in[2];   // [2,128]
    const float* Wl   = (const float*)d_in[3];   // [3,128,128]
    const float* Wr   = (const float*)d_in[4];   // [3,128,128]
    const float* Aa   = (const float*)d_in[5];   // [3,16]
    const float* Wout = (const float*)d_in[6];   // [128,1]
    float* out = (float*)d_out;                  // [4,512] fp32

    float*    ws   = (float*)d_ws;
    float*    hT_a = ws;                         // 1 MB, [4][128][512]
    float*    hT_b = ws + 262144;                // 1 MB
    uint32_t* adjb = (uint32_t*)(ws + 524288);   // 128 KB

    gat_layer<<<256, 512, 0, stream>>>(0, X, nullptr, hT_a, Win,
        Wl,               Wr,               Aa,      nullptr, out, adjb, adj);
    gat_layer<<<256, 512, 0, stream>>>(1, nullptr, hT_a, hT_b, Win,
        Wl + DH * DH,     Wr + DH * DH,     Aa + 16, nullptr, out, adjb, adj);
    gat_layer<<<256, 512, 0, stream>>>(2, nullptr, hT_b, nullptr, Win,
        Wl + 2 * DH * DH, Wr + 2 * DH * DH, Aa + 32, Wout,    out, adjb, adj);
}